// Round 2
// baseline (158.537 us; speedup 1.0000x reference)
//
#include <hip/hip_runtime.h>

// B=65536, C=2, P=41, L=4: loss = mean( ce*w + 0.001*conn )
//   ce   = relu(l_other - l_target) + log(1+exp(-|l1-l0|))
//   w    = 1 + |t[p]-t[p-1]| + |t[p+1]-t[p]| + 0.5(|t[p]-t[p-2]| + |t[p+2]-t[p]|), bounds-guarded
//   conn = (pred[p] != pred[p-1]), p>=1; pred = (l1 > l0)
//
// Round 9: 2 (b,p) pairs per thread. v7 (9 direct loads) == v8 (3 loads + LDS)
// proved the kernel is neither issue- nor redundancy-bound; this round tests
// latency/overhead-boundedness: halve the wave count (42K -> 21K), double the
// independent loads in flight per thread (6x16B), halve reduction/barrier
// overhead per element, halve the partial array (5,248 floats).
constexpr int B    = 65536;
constexpr int P    = 41;
constexpr int NTH  = B * P;          // 2,686,976
constexpr int BLK  = 256;            // threads per block
constexpr int PPB  = 512;            // (b,p) pairs per block = 2 per thread
constexpr int NBLK = NTH / PPB;      // 5,248 exactly (no tail)
constexpr float INV_N = 1.0f / (float)(B * P * 4);
constexpr float CW    = 0.001f;

__device__ __forceinline__ float comp1(float d, float dm, int tx,
                                       int am1, int ap1, int am2, int ap2)
{
    float g  = __logf(1.0f + __expf(-fabsf(d)));
    float ft = (float)tx;
    float sd = d * fmaf(-2.0f, ft, 1.0f);        // l_other - l_target
    float ce = fmaxf(sd, 0.0f) + g;

    int   x1 = (tx ^ am1) + (tx ^ ap1);          // 0..2
    int   x2 = (tx ^ am2) + (tx ^ ap2);          // 0..2
    float w  = fmaf(0.5f, (float)x2, 1.0f + (float)x1);

    float conn = ((d > 0.0f) != (dm > 0.0f)) ? CW : 0.0f;
    return fmaf(ce, w, conn);
}

// one (b,p) pair (4 lanes), reading neighbors from LDS; k = local pair index
__device__ __forceinline__ float pair4(const int4* __restrict__ stg,
                                       const float4* __restrict__ sdv,
                                       int p, int k, int4 tc, float4 d4)
{
    // clamp-to-self neighbor offsets (reproduce bounds guards exactly:
    // self XOR self = 0; self-d makes conn=0 at p=0)
    const int om1 = (p >= 1)     ? 1 : 0;
    const int op1 = (p <= P - 2) ? 1 : 0;
    const int om2 = (p >= 2)     ? 2 : 0;        // NOTE: p=1 -> self, not 0
    const int op2 = (p <= P - 3) ? 2 : 0;

    const int4   nA = stg[2 + k - om1];
    const int4   nB = stg[2 + k + op1];
    const int4   nC = stg[2 + k - om2];
    const int4   nD = stg[2 + k + op2];
    const float4 dm = sdv[1 + k - om1];

    return comp1(d4.x, dm.x, tc.x, nA.x, nB.x, nC.x, nD.x)
         + comp1(d4.y, dm.y, tc.y, nA.y, nB.y, nC.y, nD.y)
         + comp1(d4.z, dm.z, tc.z, nA.z, nB.z, nC.z, nD.z)
         + comp1(d4.w, dm.w, tc.w, nA.w, nB.w, nC.w, nD.w);
}

__global__ __launch_bounds__(256)
void lace_partial_kernel(const float4* __restrict__ lg4,
                         const int4*   __restrict__ tg4,
                         float*        __restrict__ partial)
{
    // targets at stg[k+2] (halo 2 each side), d at sdv[k+1] (halo 1 left)
    __shared__ int4   stg[PPB + 4];
    __shared__ float4 sdv[PPB + 1];

    const int tid  = threadIdx.x;
    const int base = blockIdx.x * PPB;
    const int tA   = base + tid;                 // pair A: local k = tid
    const int tB   = tA + BLK;                   // pair B: local k = tid + 256

    const int bA = tA / P;                       // magic-mul
    const int pA = tA - bA * P;
    const int fA = bA * 82 + pA;                 // float4 idx of logits[b,0,p,:]
    const int bB = tB / P;
    const int pB = tB - bB * P;
    const int fB = bB * 82 + pB;

    // ---- 6 unconditional, independent loads per thread (unique bytes only) ----
    float4 a0A = lg4[fA];
    float4 a1A = lg4[fA + 41];
    float4 a0B = lg4[fB];
    float4 a1B = lg4[fB + 41];
    int4   tcA = tg4[tA];
    int4   tcB = tg4[tB];

    // ---- halos (few lanes; clamped entries are never consumed, p-clamps see
    //      to that — the clamp is only for memory safety at the array ends) ----
    if (tid < 2)
        stg[tid] = tg4[max(base - 2 + tid, 0)];
    if (tid >= BLK - 2)
        stg[PPB + 2 + (tid - (BLK - 2))] = tg4[min(base + PPB + (tid - (BLK - 2)), NTH - 1)];
    if (tid == 0) {
        const int tm = max(base - 1, 0);
        const int bm = tm / P;
        const int pm = tm - bm * P;
        const int fm = bm * 82 + pm;
        float4 q0 = lg4[fm];
        float4 q1 = lg4[fm + 41];
        float4 dh;
        dh.x = q1.x - q0.x; dh.y = q1.y - q0.y;
        dh.z = q1.z - q0.z; dh.w = q1.w - q0.w;
        sdv[0] = dh;
    }

    float4 dA, dB;
    dA.x = a1A.x - a0A.x; dA.y = a1A.y - a0A.y;
    dA.z = a1A.z - a0A.z; dA.w = a1A.w - a0A.w;
    dB.x = a1B.x - a0B.x; dB.y = a1B.y - a0B.y;
    dB.z = a1B.z - a0B.z; dB.w = a1B.w - a0B.w;

    stg[2 + tid]        = tcA;
    stg[2 + BLK + tid]  = tcB;
    sdv[1 + tid]        = dA;
    sdv[1 + BLK + tid]  = dB;
    __syncthreads();

    float sum = pair4(stg, sdv, pA, tid,       tcA, dA)
              + pair4(stg, sdv, pB, BLK + tid, tcB, dB);

    // ---- block reduction -> one partial per block ----
    #pragma unroll
    for (int off = 32; off > 0; off >>= 1)
        sum += __shfl_down(sum, off, 64);

    __shared__ float wsum[4];
    const int lane = threadIdx.x & 63;
    const int wid  = threadIdx.x >> 6;
    if (lane == 0) wsum[wid] = sum;
    __syncthreads();
    if (threadIdx.x == 0)
        partial[blockIdx.x] = wsum[0] + wsum[1] + wsum[2] + wsum[3];
}

__global__ __launch_bounds__(1024)
void lace_reduce_kernel(const float4* __restrict__ partial4,
                        float*        __restrict__ out)
{
    constexpr int N4 = NBLK / 4;                 // 1,312 exact
    float s = 0.0f;
    for (int i = threadIdx.x; i < N4; i += 1024) {
        float4 v = partial4[i];
        s += (v.x + v.y) + (v.z + v.w);
    }

    #pragma unroll
    for (int off = 32; off > 0; off >>= 1)
        s += __shfl_down(s, off, 64);

    __shared__ float wsum[16];
    const int lane = threadIdx.x & 63;
    const int wid  = threadIdx.x >> 6;
    if (lane == 0) wsum[wid] = s;
    __syncthreads();
    if (threadIdx.x == 0) {
        float total = 0.0f;
        #pragma unroll
        for (int i = 0; i < 16; ++i) total += wsum[i];
        out[0] = total * INV_N;
    }
}

extern "C" void kernel_launch(void* const* d_in, const int* in_sizes, int n_in,
                              void* d_out, int out_size, void* d_ws, size_t ws_size,
                              hipStream_t stream) {
    const float4* lg4 = (const float4*)d_in[0];
    const int4*   tg4 = (const int4*)d_in[1];
    float* out     = (float*)d_out;
    float* partial = (float*)d_ws;   // 5,248 floats

    lace_partial_kernel<<<NBLK, BLK, 0, stream>>>(lg4, tg4, partial);
    lace_reduce_kernel<<<1, 1024, 0, stream>>>((const float4*)partial, out);
}